// Round 1
// baseline (1091.072 us; speedup 1.0000x reference)
//
#include <hip/hip_runtime.h>
#include <math.h>

#define N_NODES 100000
#define N_EDGES 1000000
#define IN_DIM 64
#define HID 64
#define NC 30
#define REG_C 0.01f

// ---------------- degree accumulation ----------------
__global__ void accum_deg(const int* __restrict__ dst, const float* __restrict__ w,
                          float* __restrict__ deg) {
    int e = blockIdx.x * blockDim.x + threadIdx.x;
    if (e < N_EDGES) atomicAdd(&deg[dst[e]], w[e]);
}

__global__ void compute_dinv(const float* __restrict__ deg, float* __restrict__ dinv,
                             float* __restrict__ invdeg) {
    int n = blockIdx.x * blockDim.x + threadIdx.x;
    if (n < N_NODES) {
        float d = deg[n] + 1.0f;       // self-loop
        dinv[n] = rsqrtf(d);
        invdeg[n] = 1.0f / d;
    }
}

// ---------------- h1 = x @ W1  (64x64) ----------------
__global__ void linear64(const float* __restrict__ X, const float* __restrict__ W,
                         float* __restrict__ H) {
    __shared__ float sW[64 * 64];
    for (int i = threadIdx.x; i < 64 * 64; i += blockDim.x) sW[i] = W[i];
    __syncthreads();
    int node = blockIdx.x * 4 + (threadIdx.x >> 6);
    int od = threadIdx.x & 63;
    if (node < N_NODES) {
        const float* xr = X + node * 64;
        float acc = 0.f;
#pragma unroll
        for (int k = 0; k < 64; ++k) acc += xr[k] * sW[k * 64 + od];
        H[node * 64 + od] = acc;
    }
}

// ---------------- edge scatter, 64-dim ----------------
__global__ void scatter64(const int* __restrict__ src, const int* __restrict__ dst,
                          const float* __restrict__ w, const float* __restrict__ dinv,
                          const float* __restrict__ h, float* __restrict__ agg) {
    int e = blockIdx.x * 4 + (threadIdx.x >> 6);
    int lane = threadIdx.x & 63;
    if (e < N_EDGES) {
        int s = src[e], d = dst[e];
        float norm = dinv[s] * w[e] * dinv[d];
        atomicAdd(&agg[d * 64 + lane], norm * h[s * 64 + lane]);
    }
}

// ---------------- self-loop + bias + relu (in place over agg -> h2) ----------------
__global__ void selfloop_relu(const float* __restrict__ h1, const float* __restrict__ invdeg,
                              const float* __restrict__ b1, float* __restrict__ agg) {
    int i = blockIdx.x * blockDim.x + threadIdx.x;  // over N*64
    if (i < N_NODES * 64) {
        int n = i >> 6, od = i & 63;
        float v = agg[i] + h1[i] * invdeg[n] + b1[od];
        agg[i] = v > 0.f ? v : 0.f;
    }
}

// ---------------- hh2 = h2 @ W2 (64x30) ----------------
__global__ void linear30(const float* __restrict__ H, const float* __restrict__ W2,
                         float* __restrict__ HH) {
    __shared__ float sW[64 * NC];
    __shared__ float sH[8 * 64];
    for (int i = threadIdx.x; i < 64 * NC; i += blockDim.x) sW[i] = W2[i];
    int node0 = blockIdx.x * 8;
    for (int i = threadIdx.x; i < 8 * 64; i += blockDim.x) {
        int n = node0 + (i >> 6);
        sH[i] = (n < N_NODES) ? H[n * 64 + (i & 63)] : 0.f;
    }
    __syncthreads();
    int ln = threadIdx.x >> 5;
    int c = threadIdx.x & 31;
    int node = node0 + ln;
    if (node < N_NODES && c < NC) {
        float acc = 0.f;
#pragma unroll
        for (int k = 0; k < 64; ++k) acc += sH[ln * 64 + k] * sW[k * NC + c];
        HH[node * NC + c] = acc;
    }
}

// ---------------- edge scatter, 30-dim ----------------
__global__ void scatter30(const int* __restrict__ src, const int* __restrict__ dst,
                          const float* __restrict__ w, const float* __restrict__ dinv,
                          const float* __restrict__ hh, float* __restrict__ agg2) {
    int e = blockIdx.x * 8 + (threadIdx.x >> 5);
    int lane = threadIdx.x & 31;
    if (e < N_EDGES && lane < NC) {
        int s = src[e], d = dst[e];
        float norm = dinv[s] * w[e] * dinv[d];
        atomicAdd(&agg2[d * NC + lane], norm * hh[s * NC + lane]);
    }
}

// ---------------- softmax -> FX, plus column-sum of log(1-FX^2) ----------------
__global__ void softmax_colsum(const float* __restrict__ agg2, const float* __restrict__ hh,
                               const float* __restrict__ invdeg, const float* __restrict__ b2,
                               float* __restrict__ FX, float* __restrict__ colsum) {
    int n = blockIdx.x * blockDim.x + threadIdx.x;
    float l[NC];
#pragma unroll
    for (int c = 0; c < NC; ++c) l[c] = 0.f;
    if (n < N_NODES) {
        float x[NC];
        float inv = invdeg[n];
        float mx = -1e30f;
#pragma unroll
        for (int c = 0; c < NC; ++c) {
            x[c] = agg2[n * NC + c] + hh[n * NC + c] * inv + b2[c];
            mx = fmaxf(mx, x[c]);
        }
        float s = 0.f;
#pragma unroll
        for (int c = 0; c < NC; ++c) { x[c] = expf(x[c] - mx); s += x[c]; }
        float si = 1.0f / s;
#pragma unroll
        for (int c = 0; c < NC; ++c) {
            float fx = x[c] * si;
            FX[n * NC + c] = fx;
            l[c] = log1pf(-fx * fx);   // log(1 - fx^2)
        }
    }
    // per-wave reduction of each cluster's partial, then one atomic per wave per c
    int lane = threadIdx.x & 63;
#pragma unroll
    for (int c = 0; c < NC; ++c) {
        float v = l[c];
        for (int off = 32; off > 0; off >>= 1) v += __shfl_down(v, off);
        if (lane == 0) atomicAdd(&colsum[c], v);
    }
}

// ---------------- per-edge FF and MSE accumulation ----------------
__global__ void edge_loss(const int* __restrict__ src, const int* __restrict__ dst,
                          const float* __restrict__ w, const float* __restrict__ FX,
                          float* __restrict__ mse) {
    int e = blockIdx.x * blockDim.x + threadIdx.x;
    float v = 0.f;
    if (e < N_EDGES) {
        int s = src[e], d = dst[e];
        float ff = 0.f;
#pragma unroll
        for (int c = 0; c < NC; ++c) ff += FX[s * NC + c] * FX[d * NC + c];
        float diff = ff - w[e];
        v = diff * diff;
    }
    for (int off = 32; off > 0; off >>= 1) v += __shfl_down(v, off);
    __shared__ float ps[4];
    int lane = threadIdx.x & 63, wv = threadIdx.x >> 6;
    if (lane == 0) ps[wv] = v;
    __syncthreads();
    if (threadIdx.x == 0) {
        atomicAdd(mse, ps[0] + ps[1] + ps[2] + ps[3]);
    }
}

// ---------------- finalize: preg + loss ----------------
__global__ void finalize(const float* __restrict__ colsum, const float* __restrict__ mse,
                         float* __restrict__ out_loss) {
    int c = threadIdx.x;
    float term = 0.f;
    if (c < NC) term = logf(1.0001f - expf(colsum[c]));
    for (int off = 32; off > 0; off >>= 1) term += __shfl_down(term, off);
    if (threadIdx.x == 0) {
        float preg = -term;
        out_loss[0] = mse[0] / (float)N_EDGES + REG_C * preg;
    }
}

extern "C" void kernel_launch(void* const* d_in, const int* in_sizes, int n_in,
                              void* d_out, int out_size, void* d_ws, size_t ws_size,
                              hipStream_t stream) {
    const float* x  = (const float*)d_in[0];
    const int*   ei = (const int*)d_in[1];
    const float* ea = (const float*)d_in[2];
    const float* W1 = (const float*)d_in[3];
    const float* b1 = (const float*)d_in[4];
    const float* W2 = (const float*)d_in[5];
    const float* b2 = (const float*)d_in[6];
    const int* srcI = ei;
    const int* dstI = ei + N_EDGES;

    float* FX   = (float*)d_out;
    float* loss = FX + (size_t)N_NODES * NC;

    float* ws     = (float*)d_ws;
    float* deg    = ws;                          // N
    float* dinv   = deg + N_NODES;               // N
    float* invdeg = dinv + N_NODES;              // N
    float* h1     = invdeg + N_NODES;            // N*64
    float* agg1   = h1 + (size_t)N_NODES * 64;   // N*64 (becomes h2)
    float* hh2    = agg1 + (size_t)N_NODES * 64; // N*30
    float* agg2   = hh2 + (size_t)N_NODES * NC;  // N*30
    float* colsum = agg2 + (size_t)N_NODES * NC; // NC
    float* mse    = colsum + NC;                 // 1

    hipMemsetAsync(deg, 0, N_NODES * sizeof(float), stream);
    hipMemsetAsync(agg1, 0, (size_t)N_NODES * 64 * sizeof(float), stream);
    hipMemsetAsync(agg2, 0, (size_t)N_NODES * NC * sizeof(float), stream);
    hipMemsetAsync(colsum, 0, (NC + 1) * sizeof(float), stream);

    accum_deg<<<(N_EDGES + 255) / 256, 256, 0, stream>>>(dstI, ea, deg);
    compute_dinv<<<(N_NODES + 255) / 256, 256, 0, stream>>>(deg, dinv, invdeg);
    linear64<<<(N_NODES + 3) / 4, 256, 0, stream>>>(x, W1, h1);
    scatter64<<<(N_EDGES + 3) / 4, 256, 0, stream>>>(srcI, dstI, ea, dinv, h1, agg1);
    selfloop_relu<<<(N_NODES * 64 + 255) / 256, 256, 0, stream>>>(h1, invdeg, b1, agg1);
    linear30<<<(N_NODES + 7) / 8, 256, 0, stream>>>(agg1, W2, hh2);
    scatter30<<<(N_EDGES + 7) / 8, 256, 0, stream>>>(srcI, dstI, ea, dinv, hh2, agg2);
    softmax_colsum<<<(N_NODES + 255) / 256, 256, 0, stream>>>(agg2, hh2, invdeg, b2, FX, colsum);
    edge_loss<<<(N_EDGES + 255) / 256, 256, 0, stream>>>(srcI, dstI, ea, FX, mse);
    finalize<<<1, 64, 0, stream>>>(colsum, mse, loss);
}

// Round 2
// 723.974 us; speedup vs baseline: 1.5071x; 1.5071x over previous
//
#include <hip/hip_runtime.h>
#include <math.h>

#define N_NODES 100000
#define N_EDGES 1000000
#define IN_DIM 64
#define HID 64
#define NC 30
#define REG_C 0.01f

// ---------------- degree accumulation ----------------
__global__ void accum_deg(const int* __restrict__ dst, const float* __restrict__ w,
                          float* __restrict__ deg) {
    int e = blockIdx.x * blockDim.x + threadIdx.x;
    if (e < N_EDGES) atomicAdd(&deg[dst[e]], w[e]);
}

__global__ void compute_dinv(const float* __restrict__ deg, float* __restrict__ dinv,
                             float* __restrict__ invdeg) {
    int n = blockIdx.x * blockDim.x + threadIdx.x;
    if (n < N_NODES) {
        float d = deg[n] + 1.0f;       // self-loop
        dinv[n] = rsqrtf(d);
        invdeg[n] = 1.0f / d;
    }
}

// ---------------- h1 = x @ W1  (64x64) ----------------
__global__ void linear64(const float* __restrict__ X, const float* __restrict__ W,
                         float* __restrict__ H) {
    __shared__ float sW[64 * 64];
    for (int i = threadIdx.x; i < 64 * 64; i += blockDim.x) sW[i] = W[i];
    __syncthreads();
    int node = blockIdx.x * 4 + (threadIdx.x >> 6);
    int od = threadIdx.x & 63;
    if (node < N_NODES) {
        const float* xr = X + node * 64;
        float acc = 0.f;
#pragma unroll
        for (int k = 0; k < 64; ++k) acc += xr[k] * sW[k * 64 + od];
        H[node * 64 + od] = acc;
    }
}

// ---------------- edge scatter, 64-dim ----------------
__global__ void scatter64(const int* __restrict__ src, const int* __restrict__ dst,
                          const float* __restrict__ w, const float* __restrict__ dinv,
                          const float* __restrict__ h, float* __restrict__ agg) {
    int e = blockIdx.x * 4 + (threadIdx.x >> 6);
    int lane = threadIdx.x & 63;
    if (e < N_EDGES) {
        int s = src[e], d = dst[e];
        float norm = dinv[s] * w[e] * dinv[d];
        atomicAdd(&agg[d * 64 + lane], norm * h[s * 64 + lane]);
    }
}

// ---------------- self-loop + bias + relu (in place over agg -> h2) ----------------
__global__ void selfloop_relu(const float* __restrict__ h1, const float* __restrict__ invdeg,
                              const float* __restrict__ b1, float* __restrict__ agg) {
    int i = blockIdx.x * blockDim.x + threadIdx.x;  // over N*64
    if (i < N_NODES * 64) {
        int n = i >> 6, od = i & 63;
        float v = agg[i] + h1[i] * invdeg[n] + b1[od];
        agg[i] = v > 0.f ? v : 0.f;
    }
}

// ---------------- hh2 = h2 @ W2 (64x30) ----------------
__global__ void linear30(const float* __restrict__ H, const float* __restrict__ W2,
                         float* __restrict__ HH) {
    __shared__ float sW[64 * NC];
    __shared__ float sH[8 * 64];
    for (int i = threadIdx.x; i < 64 * NC; i += blockDim.x) sW[i] = W2[i];
    int node0 = blockIdx.x * 8;
    for (int i = threadIdx.x; i < 8 * 64; i += blockDim.x) {
        int n = node0 + (i >> 6);
        sH[i] = (n < N_NODES) ? H[n * 64 + (i & 63)] : 0.f;
    }
    __syncthreads();
    int ln = threadIdx.x >> 5;
    int c = threadIdx.x & 31;
    int node = node0 + ln;
    if (node < N_NODES && c < NC) {
        float acc = 0.f;
#pragma unroll
        for (int k = 0; k < 64; ++k) acc += sH[ln * 64 + k] * sW[k * NC + c];
        HH[node * NC + c] = acc;
    }
}

// ---------------- edge scatter, 30-dim ----------------
__global__ void scatter30(const int* __restrict__ src, const int* __restrict__ dst,
                          const float* __restrict__ w, const float* __restrict__ dinv,
                          const float* __restrict__ hh, float* __restrict__ agg2) {
    int e = blockIdx.x * 8 + (threadIdx.x >> 5);
    int lane = threadIdx.x & 31;
    if (e < N_EDGES && lane < NC) {
        int s = src[e], d = dst[e];
        float norm = dinv[s] * w[e] * dinv[d];
        atomicAdd(&agg2[d * NC + lane], norm * hh[s * NC + lane]);
    }
}

// ---------------- softmax -> FX, plus column-sum of log(1-FX^2) ----------------
// One cluster per lane: a wave handles 2 nodes (lanes 0-29 -> node pair*2,
// lanes 32-61 -> node pair*2+1). No per-thread arrays -> no scratch spill
// (old version spilled x[30]+l[30] at VGPR_Count=40 and ran 412us latency-bound).
__global__ void softmax_colsum(const float* __restrict__ agg2, const float* __restrict__ hh,
                               const float* __restrict__ invdeg, const float* __restrict__ b2,
                               float* __restrict__ FX, float* __restrict__ colsum) {
    const int lane = threadIdx.x & 63;
    const int waveInBlock = threadIdx.x >> 6;
    const int half = lane >> 5;       // which node of the pair
    const int c = lane & 31;          // cluster slot
    const bool activeC = (c < NC);
    const int wavesTotal = gridDim.x * (blockDim.x >> 6);
    const int w0 = blockIdx.x * (blockDim.x >> 6) + waveInBlock;

    const float bb = activeC ? b2[c] : 0.f;
    float acc = 0.f;

    for (int pair = w0; pair < N_NODES / 2; pair += wavesTotal) {
        const int node = pair * 2 + half;
        float x = -INFINITY;
        if (activeC) {
            x = agg2[node * NC + c] + hh[node * NC + c] * invdeg[node] + bb;
        }
        // max over the 32-lane half (xor masks < 32 stay within the half)
        float mx = x;
        for (int off = 16; off; off >>= 1) mx = fmaxf(mx, __shfl_xor(mx, off));
        float e = activeC ? expf(x - mx) : 0.f;
        float s = e;
        for (int off = 16; off; off >>= 1) s += __shfl_xor(s, off);
        float fx = e / s;
        if (activeC) {
            FX[node * NC + c] = fx;
            acc += log1pf(-fx * fx);   // log(1 - fx^2)
        }
    }
    // combine the two halves: lane c and lane c+32 hold the same cluster
    acc += __shfl_xor(acc, 32);
    __shared__ float part[4][NC];
    if (half == 0 && activeC) part[waveInBlock][c] = acc;
    __syncthreads();
    if (threadIdx.x < NC) {
        float v = part[0][threadIdx.x] + part[1][threadIdx.x] +
                  part[2][threadIdx.x] + part[3][threadIdx.x];
        atomicAdd(&colsum[threadIdx.x], v);
    }
}

// ---------------- per-edge FF and MSE accumulation ----------------
__global__ void edge_loss(const int* __restrict__ src, const int* __restrict__ dst,
                          const float* __restrict__ w, const float* __restrict__ FX,
                          float* __restrict__ mse) {
    int e = blockIdx.x * blockDim.x + threadIdx.x;
    float v = 0.f;
    if (e < N_EDGES) {
        int s = src[e], d = dst[e];
        float ff = 0.f;
#pragma unroll
        for (int c = 0; c < NC; ++c) ff += FX[s * NC + c] * FX[d * NC + c];
        float diff = ff - w[e];
        v = diff * diff;
    }
    for (int off = 32; off > 0; off >>= 1) v += __shfl_down(v, off);
    __shared__ float ps[4];
    int lane = threadIdx.x & 63, wv = threadIdx.x >> 6;
    if (lane == 0) ps[wv] = v;
    __syncthreads();
    if (threadIdx.x == 0) {
        atomicAdd(mse, ps[0] + ps[1] + ps[2] + ps[3]);
    }
}

// ---------------- finalize: preg + loss ----------------
__global__ void finalize(const float* __restrict__ colsum, const float* __restrict__ mse,
                         float* __restrict__ out_loss) {
    int c = threadIdx.x;
    float term = 0.f;
    if (c < NC) term = logf(1.0001f - expf(colsum[c]));
    for (int off = 32; off > 0; off >>= 1) term += __shfl_down(term, off);
    if (threadIdx.x == 0) {
        float preg = -term;
        out_loss[0] = mse[0] / (float)N_EDGES + REG_C * preg;
    }
}

extern "C" void kernel_launch(void* const* d_in, const int* in_sizes, int n_in,
                              void* d_out, int out_size, void* d_ws, size_t ws_size,
                              hipStream_t stream) {
    const float* x  = (const float*)d_in[0];
    const int*   ei = (const int*)d_in[1];
    const float* ea = (const float*)d_in[2];
    const float* W1 = (const float*)d_in[3];
    const float* b1 = (const float*)d_in[4];
    const float* W2 = (const float*)d_in[5];
    const float* b2 = (const float*)d_in[6];
    const int* srcI = ei;
    const int* dstI = ei + N_EDGES;

    float* FX   = (float*)d_out;
    float* loss = FX + (size_t)N_NODES * NC;

    float* ws     = (float*)d_ws;
    float* deg    = ws;                          // N
    float* dinv   = deg + N_NODES;               // N
    float* invdeg = dinv + N_NODES;              // N
    float* h1     = invdeg + N_NODES;            // N*64
    float* agg1   = h1 + (size_t)N_NODES * 64;   // N*64 (becomes h2)
    float* hh2    = agg1 + (size_t)N_NODES * 64; // N*30
    float* agg2   = hh2 + (size_t)N_NODES * NC;  // N*30
    float* colsum = agg2 + (size_t)N_NODES * NC; // NC
    float* mse    = colsum + NC;                 // 1

    hipMemsetAsync(deg, 0, N_NODES * sizeof(float), stream);
    hipMemsetAsync(agg1, 0, (size_t)N_NODES * 64 * sizeof(float), stream);
    hipMemsetAsync(agg2, 0, (size_t)N_NODES * NC * sizeof(float), stream);
    hipMemsetAsync(colsum, 0, (NC + 1) * sizeof(float), stream);

    accum_deg<<<(N_EDGES + 255) / 256, 256, 0, stream>>>(dstI, ea, deg);
    compute_dinv<<<(N_NODES + 255) / 256, 256, 0, stream>>>(deg, dinv, invdeg);
    linear64<<<(N_NODES + 3) / 4, 256, 0, stream>>>(x, W1, h1);
    scatter64<<<(N_EDGES + 3) / 4, 256, 0, stream>>>(srcI, dstI, ea, dinv, h1, agg1);
    selfloop_relu<<<(N_NODES * 64 + 255) / 256, 256, 0, stream>>>(h1, invdeg, b1, agg1);
    linear30<<<(N_NODES + 7) / 8, 256, 0, stream>>>(agg1, W2, hh2);
    scatter30<<<(N_EDGES + 7) / 8, 256, 0, stream>>>(srcI, dstI, ea, dinv, hh2, agg2);
    softmax_colsum<<<1024, 256, 0, stream>>>(agg2, hh2, invdeg, b2, FX, colsum);
    edge_loss<<<(N_EDGES + 255) / 256, 256, 0, stream>>>(srcI, dstI, ea, FX, mse);
    finalize<<<1, 64, 0, stream>>>(colsum, mse, loss);
}

// Round 3
// 610.583 us; speedup vs baseline: 1.7869x; 1.1857x over previous
//
#include <hip/hip_runtime.h>
#include <math.h>

#define N_NODES 100000
#define N_EDGES 1000000
#define IN_DIM 64
#define HID 64
#define NC 30
#define REG_C 0.01f

#define SCAN_TILE 1024
#define SCAN_NT ((N_NODES + SCAN_TILE - 1) / SCAN_TILE)   // 98

// ---------------- histogram (count) + weighted degree, one pass ----------------
__global__ void hist_deg(const int* __restrict__ dst, const float* __restrict__ w,
                         int* __restrict__ count, float* __restrict__ deg) {
    int e = blockIdx.x * blockDim.x + threadIdx.x;
    if (e < N_EDGES) {
        int d = dst[e];
        atomicAdd(&count[d], 1);
        atomicAdd(&deg[d], w[e]);
    }
}

__global__ void compute_dinv(const float* __restrict__ deg, float* __restrict__ dinv,
                             float* __restrict__ invdeg) {
    int n = blockIdx.x * blockDim.x + threadIdx.x;
    if (n < N_NODES) {
        float d = deg[n] + 1.0f;       // self-loop
        dinv[n] = rsqrtf(d);
        invdeg[n] = 1.0f / d;
    }
}

// ---------------- 3-phase exclusive scan of count -> rowptr ----------------
__global__ void scan_p1(const int* __restrict__ count, int* __restrict__ blocksum) {
    __shared__ int s[256];
    int base = blockIdx.x * SCAN_TILE;
    int tid = threadIdx.x;
    int sum = 0;
#pragma unroll
    for (int j = 0; j < 4; ++j) {
        int i = base + tid * 4 + j;
        if (i < N_NODES) sum += count[i];
    }
    s[tid] = sum;
    __syncthreads();
    for (int off = 128; off; off >>= 1) {
        if (tid < off) s[tid] += s[tid + off];
        __syncthreads();
    }
    if (tid == 0) blocksum[blockIdx.x] = s[0];
}

__global__ void scan_p2(int* __restrict__ blocksum, int* __restrict__ rowptr) {
    __shared__ int s[128];
    int tid = threadIdx.x;
    s[tid] = (tid < SCAN_NT) ? blocksum[tid] : 0;
    __syncthreads();
    if (tid == 0) {
        int run = 0;
        for (int i = 0; i < SCAN_NT; ++i) { int v = s[i]; s[i] = run; run += v; }
        rowptr[N_NODES] = N_EDGES;   // total is a compile-time constant
    }
    __syncthreads();
    if (tid < SCAN_NT) blocksum[tid] = s[tid];
}

__global__ void scan_p3(const int* __restrict__ count, const int* __restrict__ blocksum,
                        int* __restrict__ rowptr) {
    __shared__ int s[256];
    int base = blockIdx.x * SCAN_TILE;
    int tid = threadIdx.x;
    int v[4];
    int sum = 0;
#pragma unroll
    for (int j = 0; j < 4; ++j) {
        int i = base + tid * 4 + j;
        v[j] = (i < N_NODES) ? count[i] : 0;
        sum += v[j];
    }
    s[tid] = sum;
    __syncthreads();
    // Hillis-Steele inclusive scan over 256 per-thread sums
    for (int off = 1; off < 256; off <<= 1) {
        int t = (tid >= off) ? s[tid - off] : 0;
        __syncthreads();
        s[tid] += t;
        __syncthreads();
    }
    int run = blocksum[blockIdx.x] + (tid ? s[tid - 1] : 0);
#pragma unroll
    for (int j = 0; j < 4; ++j) {
        int i = base + tid * 4 + j;
        if (i < N_NODES) rowptr[i] = run;
        run += v[j];
    }
}

// ---------------- counting-sort placement: edata[pos] = (src, norm) ----------------
__global__ void sort_scatter(const int* __restrict__ src, const int* __restrict__ dst,
                             const float* __restrict__ w, const float* __restrict__ dinv,
                             const int* __restrict__ rowptr, int* __restrict__ cursor,
                             int2* __restrict__ edata) {
    int e = blockIdx.x * blockDim.x + threadIdx.x;
    if (e < N_EDGES) {
        int s = src[e], d = dst[e];
        float norm = dinv[s] * w[e] * dinv[d];
        int pos = rowptr[d] + atomicAdd(&cursor[d], 1);
        edata[pos] = make_int2(s, __float_as_int(norm));
    }
}

// ---------------- h1 = x @ W1  (64x64) ----------------
__global__ void linear64(const float* __restrict__ X, const float* __restrict__ W,
                         float* __restrict__ H) {
    __shared__ float sW[64 * 64];
    for (int i = threadIdx.x; i < 64 * 64; i += blockDim.x) sW[i] = W[i];
    __syncthreads();
    int node = blockIdx.x * 4 + (threadIdx.x >> 6);
    int od = threadIdx.x & 63;
    if (node < N_NODES) {
        const float* xr = X + node * 64;
        float acc = 0.f;
#pragma unroll
        for (int k = 0; k < 64; ++k) acc += xr[k] * sW[k * 64 + od];
        H[node * 64 + od] = acc;
    }
}

// ---------------- gather-aggregate 64-dim + self-loop + bias + relu ----------------
// One wave per node, lane = feature dim. No atomics, single coalesced write.
__global__ void agg64_fused(const int* __restrict__ rowptr, const int2* __restrict__ edata,
                            const float* __restrict__ h1, const float* __restrict__ invdeg,
                            const float* __restrict__ b1, float* __restrict__ h2) {
    int node = blockIdx.x * 4 + (threadIdx.x >> 6);
    int lane = threadIdx.x & 63;
    if (node >= N_NODES) return;
    int p = rowptr[node], end = rowptr[node + 1];
    float acc0 = 0.f, acc1 = 0.f;
    for (; p + 1 < end; p += 2) {
        int2 e0 = edata[p];
        int2 e1 = edata[p + 1];
        acc0 += __int_as_float(e0.y) * h1[(size_t)e0.x * 64 + lane];
        acc1 += __int_as_float(e1.y) * h1[(size_t)e1.x * 64 + lane];
    }
    if (p < end) {
        int2 e0 = edata[p];
        acc0 += __int_as_float(e0.y) * h1[(size_t)e0.x * 64 + lane];
    }
    float v = acc0 + acc1 + h1[(size_t)node * 64 + lane] * invdeg[node] + b1[lane];
    h2[(size_t)node * 64 + lane] = fmaxf(v, 0.f);
}

// ---------------- hh2 = h2 @ W2 (64x30) ----------------
__global__ void linear30(const float* __restrict__ H, const float* __restrict__ W2,
                         float* __restrict__ HH) {
    __shared__ float sW[64 * NC];
    __shared__ float sH[8 * 64];
    for (int i = threadIdx.x; i < 64 * NC; i += blockDim.x) sW[i] = W2[i];
    int node0 = blockIdx.x * 8;
    for (int i = threadIdx.x; i < 8 * 64; i += blockDim.x) {
        int n = node0 + (i >> 6);
        sH[i] = (n < N_NODES) ? H[n * 64 + (i & 63)] : 0.f;
    }
    __syncthreads();
    int ln = threadIdx.x >> 5;
    int c = threadIdx.x & 31;
    int node = node0 + ln;
    if (node < N_NODES && c < NC) {
        float acc = 0.f;
#pragma unroll
        for (int k = 0; k < 64; ++k) acc += sH[ln * 64 + k] * sW[k * NC + c];
        HH[node * NC + c] = acc;
    }
}

// ---------------- gather-aggregate 30-dim + softmax -> FX + colsum, fully fused ----
// Wave = 2 nodes (lanes 0-29 node A, 32-61 node B), cluster per lane.
__global__ void agg30_softmax_colsum(const int* __restrict__ rowptr, const int2* __restrict__ edata,
                                     const float* __restrict__ hh, const float* __restrict__ invdeg,
                                     const float* __restrict__ b2, float* __restrict__ FX,
                                     float* __restrict__ colsum) {
    const int lane = threadIdx.x & 63;
    const int waveInBlock = threadIdx.x >> 6;
    const int half = lane >> 5;
    const int c = lane & 31;
    const bool activeC = (c < NC);
    const int wavesTotal = gridDim.x * (blockDim.x >> 6);
    const int w0 = blockIdx.x * (blockDim.x >> 6) + waveInBlock;

    const float bb = activeC ? b2[c] : 0.f;
    float lacc = 0.f;

    for (int pair = w0; pair < N_NODES / 2; pair += wavesTotal) {
        const int node = pair * 2 + half;
        int p = rowptr[node], end = rowptr[node + 1];
        float acc = 0.f;
        for (; p < end; ++p) {
            int2 ed = edata[p];
            if (activeC) acc += __int_as_float(ed.y) * hh[(size_t)ed.x * NC + c];
        }
        float x = activeC ? (acc + hh[(size_t)node * NC + c] * invdeg[node] + bb) : -INFINITY;
        float mx = x;
        for (int off = 16; off; off >>= 1) mx = fmaxf(mx, __shfl_xor(mx, off));
        float e = activeC ? expf(x - mx) : 0.f;
        float s = e;
        for (int off = 16; off; off >>= 1) s += __shfl_xor(s, off);
        float fx = e / s;
        if (activeC) {
            FX[(size_t)node * NC + c] = fx;
            lacc += log1pf(-fx * fx);
        }
    }
    lacc += __shfl_xor(lacc, 32);
    __shared__ float part[4][NC];
    if (half == 0 && activeC) part[waveInBlock][c] = lacc;
    __syncthreads();
    if (threadIdx.x < NC) {
        float v = part[0][threadIdx.x] + part[1][threadIdx.x] +
                  part[2][threadIdx.x] + part[3][threadIdx.x];
        atomicAdd(&colsum[threadIdx.x], v);
    }
}

// ---------------- per-edge FF and MSE accumulation ----------------
__global__ void edge_loss(const int* __restrict__ src, const int* __restrict__ dst,
                          const float* __restrict__ w, const float* __restrict__ FX,
                          float* __restrict__ mse) {
    int e = blockIdx.x * blockDim.x + threadIdx.x;
    float v = 0.f;
    if (e < N_EDGES) {
        int s = src[e], d = dst[e];
        float ff = 0.f;
#pragma unroll
        for (int c = 0; c < NC; ++c) ff += FX[(size_t)s * NC + c] * FX[(size_t)d * NC + c];
        float diff = ff - w[e];
        v = diff * diff;
    }
    for (int off = 32; off > 0; off >>= 1) v += __shfl_down(v, off);
    __shared__ float ps[4];
    int lane = threadIdx.x & 63, wv = threadIdx.x >> 6;
    if (lane == 0) ps[wv] = v;
    __syncthreads();
    if (threadIdx.x == 0) atomicAdd(mse, ps[0] + ps[1] + ps[2] + ps[3]);
}

// ---------------- finalize: preg + loss ----------------
__global__ void finalize(const float* __restrict__ colsum, const float* __restrict__ mse,
                         float* __restrict__ out_loss) {
    int c = threadIdx.x;
    float term = 0.f;
    if (c < NC) term = logf(1.0001f - expf(colsum[c]));
    for (int off = 32; off > 0; off >>= 1) term += __shfl_down(term, off);
    if (threadIdx.x == 0) {
        float preg = -term;
        out_loss[0] = mse[0] / (float)N_EDGES + REG_C * preg;
    }
}

extern "C" void kernel_launch(void* const* d_in, const int* in_sizes, int n_in,
                              void* d_out, int out_size, void* d_ws, size_t ws_size,
                              hipStream_t stream) {
    const float* x  = (const float*)d_in[0];
    const int*   ei = (const int*)d_in[1];
    const float* ea = (const float*)d_in[2];
    const float* W1 = (const float*)d_in[3];
    const float* b1 = (const float*)d_in[4];
    const float* W2 = (const float*)d_in[5];
    const float* b2 = (const float*)d_in[6];
    const int* srcI = ei;
    const int* dstI = ei + N_EDGES;

    float* FX   = (float*)d_out;
    float* loss = FX + (size_t)N_NODES * NC;

    // workspace layout (floats/ints are both 4B; edata needs 8B alignment --
    // its element offset below is even)
    float* ws     = (float*)d_ws;
    float* deg    = ws;                            // N
    float* dinv   = deg + N_NODES;                 // N
    float* invdeg = dinv + N_NODES;                // N
    float* h1     = invdeg + N_NODES;              // N*64
    float* h2     = h1 + (size_t)N_NODES * 64;     // N*64
    float* hh2    = h2 + (size_t)N_NODES * 64;     // N*30
    float* colsum = hh2 + (size_t)N_NODES * NC;    // NC
    float* mse    = colsum + NC;                   // 1
    int*   count  = (int*)(mse + 1);               // N
    int*   cursor = count + N_NODES;               // N
    int*   rowptr = cursor + N_NODES;              // N+1
    int*   bsum   = rowptr + N_NODES + 1;          // 128
    // running element offset: 3N + 128N + 30N + 31 + 3N + 1 + 128 = 164*N + 160 (even)
    int2*  edata  = (int2*)(bsum + 128);           // E int2 = 8 MB

    hipMemsetAsync(deg, 0, N_NODES * sizeof(float), stream);
    hipMemsetAsync(count, 0, N_NODES * sizeof(int), stream);
    hipMemsetAsync(cursor, 0, N_NODES * sizeof(int), stream);
    hipMemsetAsync(colsum, 0, (NC + 1) * sizeof(float), stream);

    hist_deg<<<(N_EDGES + 255) / 256, 256, 0, stream>>>(dstI, ea, count, deg);
    compute_dinv<<<(N_NODES + 255) / 256, 256, 0, stream>>>(deg, dinv, invdeg);
    scan_p1<<<SCAN_NT, 256, 0, stream>>>(count, bsum);
    scan_p2<<<1, 128, 0, stream>>>(bsum, rowptr);
    scan_p3<<<SCAN_NT, 256, 0, stream>>>(count, bsum, rowptr);
    sort_scatter<<<(N_EDGES + 255) / 256, 256, 0, stream>>>(srcI, dstI, ea, dinv,
                                                            rowptr, cursor, edata);
    linear64<<<(N_NODES + 3) / 4, 256, 0, stream>>>(x, W1, h1);
    agg64_fused<<<(N_NODES + 3) / 4, 256, 0, stream>>>(rowptr, edata, h1, invdeg, b1, h2);
    linear30<<<(N_NODES + 7) / 8, 256, 0, stream>>>(h2, W2, hh2);
    agg30_softmax_colsum<<<1024, 256, 0, stream>>>(rowptr, edata, hh2, invdeg, b2, FX, colsum);
    edge_loss<<<(N_EDGES + 255) / 256, 256, 0, stream>>>(srcI, dstI, ea, FX, mse);
    finalize<<<1, 64, 0, stream>>>(colsum, mse, loss);
}

// Round 4
// 583.211 us; speedup vs baseline: 1.8708x; 1.0469x over previous
//
#include <hip/hip_runtime.h>
#include <hip/hip_fp16.h>
#include <math.h>

#define N_NODES 100000
#define N_EDGES 1000000
#define IN_DIM 64
#define HID 64
#define NC 30
#define NCP 32              // padded row width for fp16 feature rows (64 B)
#define REG_C 0.01f

#define SCAN_TILE 1024
#define SCAN_NT ((N_NODES + SCAN_TILE - 1) / SCAN_TILE)   // 98

// ---------------- histogram (count) + weighted degree, one pass ----------------
__global__ void hist_deg(const int* __restrict__ dst, const float* __restrict__ w,
                         int* __restrict__ count, float* __restrict__ deg) {
    int e = blockIdx.x * blockDim.x + threadIdx.x;
    if (e < N_EDGES) {
        int d = dst[e];
        atomicAdd(&count[d], 1);
        atomicAdd(&deg[d], w[e]);
    }
}

__global__ void compute_dinv(const float* __restrict__ deg, float* __restrict__ dinv,
                             float* __restrict__ invdeg) {
    int n = blockIdx.x * blockDim.x + threadIdx.x;
    if (n < N_NODES) {
        float d = deg[n] + 1.0f;       // self-loop
        dinv[n] = rsqrtf(d);
        invdeg[n] = 1.0f / d;
    }
}

// ---------------- 3-phase exclusive scan of count -> rowptr ----------------
__global__ void scan_p1(const int* __restrict__ count, int* __restrict__ blocksum) {
    __shared__ int s[256];
    int base = blockIdx.x * SCAN_TILE;
    int tid = threadIdx.x;
    int sum = 0;
#pragma unroll
    for (int j = 0; j < 4; ++j) {
        int i = base + tid * 4 + j;
        if (i < N_NODES) sum += count[i];
    }
    s[tid] = sum;
    __syncthreads();
    for (int off = 128; off; off >>= 1) {
        if (tid < off) s[tid] += s[tid + off];
        __syncthreads();
    }
    if (tid == 0) blocksum[blockIdx.x] = s[0];
}

__global__ void scan_p2(int* __restrict__ blocksum, int* __restrict__ rowptr) {
    __shared__ int s[128];
    int tid = threadIdx.x;
    s[tid] = (tid < SCAN_NT) ? blocksum[tid] : 0;
    __syncthreads();
    if (tid == 0) {
        int run = 0;
        for (int i = 0; i < SCAN_NT; ++i) { int v = s[i]; s[i] = run; run += v; }
        rowptr[N_NODES] = N_EDGES;
    }
    __syncthreads();
    if (tid < SCAN_NT) blocksum[tid] = s[tid];
}

__global__ void scan_p3(const int* __restrict__ count, const int* __restrict__ blocksum,
                        int* __restrict__ rowptr) {
    __shared__ int s[256];
    int base = blockIdx.x * SCAN_TILE;
    int tid = threadIdx.x;
    int v[4];
    int sum = 0;
#pragma unroll
    for (int j = 0; j < 4; ++j) {
        int i = base + tid * 4 + j;
        v[j] = (i < N_NODES) ? count[i] : 0;
        sum += v[j];
    }
    s[tid] = sum;
    __syncthreads();
    for (int off = 1; off < 256; off <<= 1) {
        int t = (tid >= off) ? s[tid - off] : 0;
        __syncthreads();
        s[tid] += t;
        __syncthreads();
    }
    int run = blocksum[blockIdx.x] + (tid ? s[tid - 1] : 0);
#pragma unroll
    for (int j = 0; j < 4; ++j) {
        int i = base + tid * 4 + j;
        if (i < N_NODES) rowptr[i] = run;
        run += v[j];
    }
}

// ---------------- counting-sort placement: edata[pos]=(src,norm), w_sorted[pos]=w ----
__global__ void sort_scatter(const int* __restrict__ src, const int* __restrict__ dst,
                             const float* __restrict__ w, const float* __restrict__ dinv,
                             const int* __restrict__ rowptr, int* __restrict__ cursor,
                             int2* __restrict__ edata, float* __restrict__ w_sorted) {
    int e = blockIdx.x * blockDim.x + threadIdx.x;
    if (e < N_EDGES) {
        int s = src[e], d = dst[e];
        float norm = dinv[s] * w[e] * dinv[d];
        int pos = rowptr[d] + atomicAdd(&cursor[d], 1);
        edata[pos] = make_int2(s, __float_as_int(norm));
        w_sorted[pos] = w[e];
    }
}

// ---------------- h1 = x @ W1  (64x64) ----------------
__global__ void linear64(const float* __restrict__ X, const float* __restrict__ W,
                         float* __restrict__ H) {
    __shared__ float sW[64 * 64];
    for (int i = threadIdx.x; i < 64 * 64; i += blockDim.x) sW[i] = W[i];
    __syncthreads();
    int node = blockIdx.x * 4 + (threadIdx.x >> 6);
    int od = threadIdx.x & 63;
    if (node < N_NODES) {
        const float* xr = X + node * 64;
        float acc = 0.f;
#pragma unroll
        for (int k = 0; k < 64; ++k) acc += xr[k] * sW[k * 64 + od];
        H[node * 64 + od] = acc;
    }
}

// ---------------- gather-aggregate 64-dim + self-loop + bias + relu ----------------
__global__ void agg64_fused(const int* __restrict__ rowptr, const int2* __restrict__ edata,
                            const float* __restrict__ h1, const float* __restrict__ invdeg,
                            const float* __restrict__ b1, float* __restrict__ h2) {
    int node = blockIdx.x * 4 + (threadIdx.x >> 6);
    int lane = threadIdx.x & 63;
    if (node >= N_NODES) return;
    int p = rowptr[node], end = rowptr[node + 1];
    float a0 = 0.f, a1 = 0.f, a2 = 0.f, a3 = 0.f;
    for (; p + 3 < end; p += 4) {
        int2 e0 = edata[p], e1 = edata[p + 1], e2 = edata[p + 2], e3 = edata[p + 3];
        a0 += __int_as_float(e0.y) * h1[(size_t)e0.x * 64 + lane];
        a1 += __int_as_float(e1.y) * h1[(size_t)e1.x * 64 + lane];
        a2 += __int_as_float(e2.y) * h1[(size_t)e2.x * 64 + lane];
        a3 += __int_as_float(e3.y) * h1[(size_t)e3.x * 64 + lane];
    }
    for (; p < end; ++p) {
        int2 e0 = edata[p];
        a0 += __int_as_float(e0.y) * h1[(size_t)e0.x * 64 + lane];
    }
    float v = (a0 + a1) + (a2 + a3) + h1[(size_t)node * 64 + lane] * invdeg[node] + b1[lane];
    h2[(size_t)node * 64 + lane] = fmaxf(v, 0.f);
}

// ---------------- hh16 = fp16(h2 @ W2), padded 32-wide rows (64 B, zero-filled) ----
__global__ void linear30(const float* __restrict__ H, const float* __restrict__ W2,
                         __half* __restrict__ HH16) {
    __shared__ float sW[64 * NC];
    __shared__ float sH[8 * 64];
    for (int i = threadIdx.x; i < 64 * NC; i += blockDim.x) sW[i] = W2[i];
    int node0 = blockIdx.x * 8;
    for (int i = threadIdx.x; i < 8 * 64; i += blockDim.x) {
        int n = node0 + (i >> 6);
        sH[i] = (n < N_NODES) ? H[n * 64 + (i & 63)] : 0.f;
    }
    __syncthreads();
    int ln = threadIdx.x >> 5;
    int c = threadIdx.x & 31;
    int node = node0 + ln;
    if (node < N_NODES) {
        float acc = 0.f;
        if (c < NC) {
#pragma unroll
            for (int k = 0; k < 64; ++k) acc += sH[ln * 64 + k] * sW[k * NC + c];
        }
        HH16[(size_t)node * NCP + c] = __float2half(acc);   // c>=NC writes 0
    }
}

// ---------------- gather-aggregate 30-dim + softmax -> FX/FX16 + colsum ------------
// Wave = 2 nodes (lanes 0-29 node A, 32-61 node B), cluster per lane.
// hh16 rows are 64 B aligned -> one line per gather. Unroll-2 for ILP.
__global__ void agg30_softmax_colsum(const int* __restrict__ rowptr, const int2* __restrict__ edata,
                                     const __half* __restrict__ HH16,
                                     const float* __restrict__ invdeg,
                                     const float* __restrict__ b2, float* __restrict__ FX,
                                     __half* __restrict__ FX16, float* __restrict__ colsum) {
    const int lane = threadIdx.x & 63;
    const int waveInBlock = threadIdx.x >> 6;
    const int half = lane >> 5;
    const int c = lane & 31;
    const bool activeC = (c < NC);
    const int wavesTotal = gridDim.x * (blockDim.x >> 6);
    const int w0 = blockIdx.x * (blockDim.x >> 6) + waveInBlock;

    const float bb = activeC ? b2[c] : 0.f;
    float lacc = 0.f;

    for (int pair = w0; pair < N_NODES / 2; pair += wavesTotal) {
        const int node = pair * 2 + half;
        int p = rowptr[node], end = rowptr[node + 1];
        float acc0 = 0.f, acc1 = 0.f;
        for (; p + 1 < end; p += 2) {
            int2 e0 = edata[p];
            int2 e1 = edata[p + 1];
            float v0 = __half2float(HH16[(size_t)e0.x * NCP + c]);
            float v1 = __half2float(HH16[(size_t)e1.x * NCP + c]);
            acc0 += __int_as_float(e0.y) * v0;
            acc1 += __int_as_float(e1.y) * v1;
        }
        if (p < end) {
            int2 e0 = edata[p];
            acc0 += __int_as_float(e0.y) * __half2float(HH16[(size_t)e0.x * NCP + c]);
        }
        float selfv = __half2float(HH16[(size_t)node * NCP + c]);
        float x = activeC ? (acc0 + acc1 + selfv * invdeg[node] + bb) : -INFINITY;
        float mx = x;
        for (int off = 16; off; off >>= 1) mx = fmaxf(mx, __shfl_xor(mx, off));
        float e = activeC ? expf(x - mx) : 0.f;
        float s = e;
        for (int off = 16; off; off >>= 1) s += __shfl_xor(s, off);
        float fx = e / s;
        if (activeC) {
            FX[(size_t)node * NC + c] = fx;
            FX16[(size_t)node * NCP + c] = __float2half(fx);
            lacc += log1pf(-fx * fx);
        } else {
            FX16[(size_t)node * NCP + c] = __float2half(0.f);  // zero the pad
        }
    }
    lacc += __shfl_xor(lacc, 32);
    __shared__ float part[4][NC];
    if (half == 0 && activeC) part[waveInBlock][c] = lacc;
    __syncthreads();
    if (threadIdx.x < NC) {
        float v = part[0][threadIdx.x] + part[1][threadIdx.x] +
                  part[2][threadIdx.x] + part[3][threadIdx.x];
        atomicAdd(&colsum[threadIdx.x], v);
    }
}

// ---------------- node-centric edge loss over CSR ----------------
// Wave = 2 nodes; dst row (FX16[d]) stays in registers; gather only FX16[src].
__global__ void edge_loss_csr(const int* __restrict__ rowptr, const int2* __restrict__ edata,
                              const float* __restrict__ w_sorted,
                              const __half* __restrict__ FX16, float* __restrict__ mse) {
    const int lane = threadIdx.x & 63;
    const int waveInBlock = threadIdx.x >> 6;
    const int half = lane >> 5;
    const int c = lane & 31;
    const int wavesTotal = gridDim.x * (blockDim.x >> 6);
    const int w0 = blockIdx.x * (blockDim.x >> 6) + waveInBlock;

    float acc = 0.f;
    for (int pair = w0; pair < N_NODES / 2; pair += wavesTotal) {
        const int node = pair * 2 + half;
        const float fxd = __half2float(FX16[(size_t)node * NCP + c]);  // pad lanes get 0
        int p = rowptr[node], end = rowptr[node + 1];
        for (; p + 1 < end; p += 2) {
            int2 e0 = edata[p];
            int2 e1 = edata[p + 1];
            float p0 = __half2float(FX16[(size_t)e0.x * NCP + c]) * fxd;
            float p1 = __half2float(FX16[(size_t)e1.x * NCP + c]) * fxd;
            for (int off = 16; off; off >>= 1) {
                p0 += __shfl_xor(p0, off);
                p1 += __shfl_xor(p1, off);
            }
            float d0 = p0 - w_sorted[p];
            float d1 = p1 - w_sorted[p + 1];
            if (c == 0) acc += d0 * d0 + d1 * d1;
        }
        if (p < end) {
            int2 e0 = edata[p];
            float p0 = __half2float(FX16[(size_t)e0.x * NCP + c]) * fxd;
            for (int off = 16; off; off >>= 1) p0 += __shfl_xor(p0, off);
            float d0 = p0 - w_sorted[p];
            if (c == 0) acc += d0 * d0;
        }
    }
    acc += __shfl_xor(acc, 32);   // combine the two halves onto lane 0
    __shared__ float ps[4];
    if (lane == 0) ps[waveInBlock] = acc;
    __syncthreads();
    if (threadIdx.x == 0) atomicAdd(mse, ps[0] + ps[1] + ps[2] + ps[3]);
}

// ---------------- finalize: preg + loss ----------------
__global__ void finalize(const float* __restrict__ colsum, const float* __restrict__ mse,
                         float* __restrict__ out_loss) {
    int c = threadIdx.x;
    float term = 0.f;
    if (c < NC) term = logf(1.0001f - expf(colsum[c]));
    for (int off = 32; off > 0; off >>= 1) term += __shfl_down(term, off);
    if (threadIdx.x == 0) {
        float preg = -term;
        out_loss[0] = mse[0] / (float)N_EDGES + REG_C * preg;
    }
}

extern "C" void kernel_launch(void* const* d_in, const int* in_sizes, int n_in,
                              void* d_out, int out_size, void* d_ws, size_t ws_size,
                              hipStream_t stream) {
    const float* x  = (const float*)d_in[0];
    const int*   ei = (const int*)d_in[1];
    const float* ea = (const float*)d_in[2];
    const float* W1 = (const float*)d_in[3];
    const float* b1 = (const float*)d_in[4];
    const float* W2 = (const float*)d_in[5];
    const float* b2 = (const float*)d_in[6];
    const int* srcI = ei;
    const int* dstI = ei + N_EDGES;

    float* FX   = (float*)d_out;
    float* loss = FX + (size_t)N_NODES * NC;

    // workspace layout (element offsets chosen for 8 B / 64 B alignment)
    float* ws     = (float*)d_ws;
    float* deg    = ws;                            // N
    float* dinv   = deg + N_NODES;                 // N
    float* invdeg = dinv + N_NODES;                // N
    float* h1     = invdeg + N_NODES;              // 64N (fp32, dead after agg64)
    // hh16/FX16 reuse h1's region after agg64_fused completes (stream-ordered):
    __half* hh16  = (__half*)h1;                   // N*32 halves = 16N floats
    __half* fx16  = (__half*)(h1 + (size_t)16 * N_NODES);  // next 16N floats
    float* h2     = h1 + (size_t)N_NODES * 64;     // 64N
    float* colsum = h2 + (size_t)N_NODES * 64;     // 32
    float* mse    = colsum + 32;                   // 1
    int*   count  = (int*)(mse + 1);               // N
    int*   cursor = count + N_NODES;               // N
    int*   rowptr = cursor + N_NODES;              // N+1
    int*   bsum   = rowptr + N_NODES + 1;          // 128 (+2 pad -> even offset)
    int2*  edata  = (int2*)(bsum + 130);           // E int2 = 8 MB
    float* w_sorted = (float*)(edata + N_EDGES);   // E

    hipMemsetAsync(deg, 0, N_NODES * sizeof(float), stream);
    hipMemsetAsync(count, 0, N_NODES * sizeof(int), stream);
    hipMemsetAsync(cursor, 0, N_NODES * sizeof(int), stream);
    hipMemsetAsync(colsum, 0, 33 * sizeof(float), stream);

    hist_deg<<<(N_EDGES + 255) / 256, 256, 0, stream>>>(dstI, ea, count, deg);
    compute_dinv<<<(N_NODES + 255) / 256, 256, 0, stream>>>(deg, dinv, invdeg);
    scan_p1<<<SCAN_NT, 256, 0, stream>>>(count, bsum);
    scan_p2<<<1, 128, 0, stream>>>(bsum, rowptr);
    scan_p3<<<SCAN_NT, 256, 0, stream>>>(count, bsum, rowptr);
    sort_scatter<<<(N_EDGES + 255) / 256, 256, 0, stream>>>(srcI, dstI, ea, dinv,
                                                            rowptr, cursor, edata, w_sorted);
    linear64<<<(N_NODES + 3) / 4, 256, 0, stream>>>(x, W1, h1);
    agg64_fused<<<(N_NODES + 3) / 4, 256, 0, stream>>>(rowptr, edata, h1, invdeg, b1, h2);
    linear30<<<(N_NODES + 7) / 8, 256, 0, stream>>>(h2, W2, hh16);
    agg30_softmax_colsum<<<1024, 256, 0, stream>>>(rowptr, edata, hh16, invdeg, b2,
                                                   FX, fx16, colsum);
    edge_loss_csr<<<1024, 256, 0, stream>>>(rowptr, edata, w_sorted, fx16, mse);
    finalize<<<1, 64, 0, stream>>>(colsum, mse, loss);
}

// Round 5
// 467.723 us; speedup vs baseline: 2.3327x; 1.2469x over previous
//
#include <hip/hip_runtime.h>
#include <hip/hip_fp16.h>
#include <math.h>

#define N_NODES 100000
#define N_EDGES 1000000
#define IN_DIM 64
#define HID 64
#define NC 30
#define NCP 32              // padded row width for fp16 feature rows (64 B)
#define REG_C 0.01f

#define SCAN_TILE 1024
#define SCAN_NT ((N_NODES + SCAN_TILE - 1) / SCAN_TILE)   // 98
#define NTILES (N_NODES / 16)                             // 6250 exactly

typedef _Float16 half8 __attribute__((ext_vector_type(8)));
typedef float f32x4 __attribute__((ext_vector_type(4)));

// ---------------- histogram (count) + weighted degree, one pass ----------------
__global__ void hist_deg(const int* __restrict__ dst, const float* __restrict__ w,
                         int* __restrict__ count, float* __restrict__ deg) {
    int e = blockIdx.x * blockDim.x + threadIdx.x;
    if (e < N_EDGES) {
        int d = dst[e];
        atomicAdd(&count[d], 1);
        atomicAdd(&deg[d], w[e]);
    }
}

__global__ void compute_dinv(const float* __restrict__ deg, float* __restrict__ dinv,
                             float* __restrict__ invdeg) {
    int n = blockIdx.x * blockDim.x + threadIdx.x;
    if (n < N_NODES) {
        float d = deg[n] + 1.0f;       // self-loop
        dinv[n] = rsqrtf(d);
        invdeg[n] = 1.0f / d;
    }
}

// ---------------- 3-phase exclusive scan of count -> rowptr ----------------
__global__ void scan_p1(const int* __restrict__ count, int* __restrict__ blocksum) {
    __shared__ int s[256];
    int base = blockIdx.x * SCAN_TILE;
    int tid = threadIdx.x;
    int sum = 0;
#pragma unroll
    for (int j = 0; j < 4; ++j) {
        int i = base + tid * 4 + j;
        if (i < N_NODES) sum += count[i];
    }
    s[tid] = sum;
    __syncthreads();
    for (int off = 128; off; off >>= 1) {
        if (tid < off) s[tid] += s[tid + off];
        __syncthreads();
    }
    if (tid == 0) blocksum[blockIdx.x] = s[0];
}

__global__ void scan_p2(int* __restrict__ blocksum, int* __restrict__ rowptr) {
    __shared__ int s[128];
    int tid = threadIdx.x;
    s[tid] = (tid < SCAN_NT) ? blocksum[tid] : 0;
    __syncthreads();
    if (tid == 0) {
        int run = 0;
        for (int i = 0; i < SCAN_NT; ++i) { int v = s[i]; s[i] = run; run += v; }
        rowptr[N_NODES] = N_EDGES;
    }
    __syncthreads();
    if (tid < SCAN_NT) blocksum[tid] = s[tid];
}

__global__ void scan_p3(const int* __restrict__ count, const int* __restrict__ blocksum,
                        int* __restrict__ rowptr) {
    __shared__ int s[256];
    int base = blockIdx.x * SCAN_TILE;
    int tid = threadIdx.x;
    int v[4];
    int sum = 0;
#pragma unroll
    for (int j = 0; j < 4; ++j) {
        int i = base + tid * 4 + j;
        v[j] = (i < N_NODES) ? count[i] : 0;
        sum += v[j];
    }
    s[tid] = sum;
    __syncthreads();
    for (int off = 1; off < 256; off <<= 1) {
        int t = (tid >= off) ? s[tid - off] : 0;
        __syncthreads();
        s[tid] += t;
        __syncthreads();
    }
    int run = blocksum[blockIdx.x] + (tid ? s[tid - 1] : 0);
#pragma unroll
    for (int j = 0; j < 4; ++j) {
        int i = base + tid * 4 + j;
        if (i < N_NODES) rowptr[i] = run;
        run += v[j];
    }
}

// ---------------- counting-sort placement: edata[pos]=(src,norm) ----------------
__global__ void sort_scatter(const int* __restrict__ src, const int* __restrict__ dst,
                             const float* __restrict__ w, const float* __restrict__ dinv,
                             const int* __restrict__ rowptr, int* __restrict__ cursor,
                             int2* __restrict__ edata) {
    int e = blockIdx.x * blockDim.x + threadIdx.x;
    if (e < N_EDGES) {
        int s = src[e], d = dst[e];
        float norm = dinv[s] * w[e] * dinv[d];
        int pos = rowptr[d] + atomicAdd(&cursor[d], 1);
        edata[pos] = make_int2(s, __float_as_int(norm));
    }
}

// ---------------- h1 = fp16(x @ W1) via MFMA 16x16x32 f16 ----------------
// Wave holds all B-frags (W1, 4 N-tiles x 2 K-blocks) in registers; grid-stride
// over 16-node M-tiles. C/D layout: col=lane&15, row=(lane>>4)*4+reg.
// A layout: A[m=lane&15][k=(lane>>4)*8+j]; B: B[k=(lane>>4)*8+j][n=lane&15].
__global__ void linear64_mfma(const float* __restrict__ X, const float* __restrict__ W,
                              _Float16* __restrict__ H16) {
    const int lane = threadIdx.x & 63;
    const int wave = threadIdx.x >> 6;
    const int q = lane >> 4;       // quad
    const int l = lane & 15;

    // B fragments: bfrag[kb][t][j] = W[(kb*32 + q*8 + j)*64 + t*16 + l]
    half8 bfrag[2][4];
#pragma unroll
    for (int kb = 0; kb < 2; ++kb)
#pragma unroll
        for (int t = 0; t < 4; ++t)
#pragma unroll
            for (int j = 0; j < 8; ++j)
                bfrag[kb][t][j] = (_Float16)W[(kb * 32 + q * 8 + j) * 64 + t * 16 + l];

    const int waveStride = gridDim.x * 4;
    for (int ntile = blockIdx.x * 4 + wave; ntile < NTILES; ntile += waveStride) {
        const int node0 = ntile * 16;
        const float* arow = X + (size_t)(node0 + l) * 64 + q * 8;
        half8 af0, af1;
#pragma unroll
        for (int j = 0; j < 8; ++j) {
            af0[j] = (_Float16)arow[j];
            af1[j] = (_Float16)arow[32 + j];
        }
        f32x4 acc[4];
#pragma unroll
        for (int t = 0; t < 4; ++t) acc[t] = (f32x4){0.f, 0.f, 0.f, 0.f};
#pragma unroll
        for (int t = 0; t < 4; ++t) {
            acc[t] = __builtin_amdgcn_mfma_f32_16x16x32_f16(af0, bfrag[0][t], acc[t], 0, 0, 0);
            acc[t] = __builtin_amdgcn_mfma_f32_16x16x32_f16(af1, bfrag[1][t], acc[t], 0, 0, 0);
        }
#pragma unroll
        for (int t = 0; t < 4; ++t)
#pragma unroll
            for (int r = 0; r < 4; ++r)
                H16[(size_t)(node0 + q * 4 + r) * 64 + t * 16 + l] = (_Float16)acc[t][r];
    }
}

// ---------------- gather-aggregate 64-dim (fp16 rows) + self-loop + bias + relu ----
__global__ void agg64_fused(const int* __restrict__ rowptr, const int2* __restrict__ edata,
                            const _Float16* __restrict__ H16, const float* __restrict__ invdeg,
                            const float* __restrict__ b1, float* __restrict__ h2) {
    int node = blockIdx.x * 4 + (threadIdx.x >> 6);
    int lane = threadIdx.x & 63;
    if (node >= N_NODES) return;
    int p = rowptr[node], end = rowptr[node + 1];
    float a0 = 0.f, a1 = 0.f, a2 = 0.f, a3 = 0.f;
    for (; p + 3 < end; p += 4) {
        int2 e0 = edata[p], e1 = edata[p + 1], e2 = edata[p + 2], e3 = edata[p + 3];
        a0 += __int_as_float(e0.y) * (float)H16[(size_t)e0.x * 64 + lane];
        a1 += __int_as_float(e1.y) * (float)H16[(size_t)e1.x * 64 + lane];
        a2 += __int_as_float(e2.y) * (float)H16[(size_t)e2.x * 64 + lane];
        a3 += __int_as_float(e3.y) * (float)H16[(size_t)e3.x * 64 + lane];
    }
    for (; p < end; ++p) {
        int2 e0 = edata[p];
        a0 += __int_as_float(e0.y) * (float)H16[(size_t)e0.x * 64 + lane];
    }
    float v = (a0 + a1) + (a2 + a3) +
              (float)H16[(size_t)node * 64 + lane] * invdeg[node] + b1[lane];
    h2[(size_t)node * 64 + lane] = fmaxf(v, 0.f);
}

// ---------------- hh16 = fp16(h2 @ W2), padded 32-wide rows (64 B, zero-filled) ----
__global__ void linear30(const float* __restrict__ H, const float* __restrict__ W2,
                         __half* __restrict__ HH16) {
    __shared__ float sW[64 * NC];
    __shared__ float sH[8 * 64];
    for (int i = threadIdx.x; i < 64 * NC; i += blockDim.x) sW[i] = W2[i];
    int node0 = blockIdx.x * 8;
    for (int i = threadIdx.x; i < 8 * 64; i += blockDim.x) {
        int n = node0 + (i >> 6);
        sH[i] = (n < N_NODES) ? H[n * 64 + (i & 63)] : 0.f;
    }
    __syncthreads();
    int ln = threadIdx.x >> 5;
    int c = threadIdx.x & 31;
    int node = node0 + ln;
    if (node < N_NODES) {
        float acc = 0.f;
        if (c < NC) {
#pragma unroll
            for (int k = 0; k < 64; ++k) acc += sH[ln * 64 + k] * sW[k * NC + c];
        }
        HH16[(size_t)node * NCP + c] = __float2half(acc);   // c>=NC writes 0
    }
}

// ---------------- gather-aggregate 30-dim + softmax -> FX/FX16 + colsum ------------
__global__ void agg30_softmax_colsum(const int* __restrict__ rowptr, const int2* __restrict__ edata,
                                     const __half* __restrict__ HH16,
                                     const float* __restrict__ invdeg,
                                     const float* __restrict__ b2, float* __restrict__ FX,
                                     __half* __restrict__ FX16, float* __restrict__ colsum) {
    const int lane = threadIdx.x & 63;
    const int waveInBlock = threadIdx.x >> 6;
    const int half = lane >> 5;
    const int c = lane & 31;
    const bool activeC = (c < NC);
    const int wavesTotal = gridDim.x * (blockDim.x >> 6);
    const int w0 = blockIdx.x * (blockDim.x >> 6) + waveInBlock;

    const float bb = activeC ? b2[c] : 0.f;
    float lacc = 0.f;

    for (int pair = w0; pair < N_NODES / 2; pair += wavesTotal) {
        const int node = pair * 2 + half;
        int p = rowptr[node], end = rowptr[node + 1];
        float acc0 = 0.f, acc1 = 0.f;
        for (; p + 1 < end; p += 2) {
            int2 e0 = edata[p];
            int2 e1 = edata[p + 1];
            float v0 = __half2float(HH16[(size_t)e0.x * NCP + c]);
            float v1 = __half2float(HH16[(size_t)e1.x * NCP + c]);
            acc0 += __int_as_float(e0.y) * v0;
            acc1 += __int_as_float(e1.y) * v1;
        }
        if (p < end) {
            int2 e0 = edata[p];
            acc0 += __int_as_float(e0.y) * __half2float(HH16[(size_t)e0.x * NCP + c]);
        }
        float selfv = __half2float(HH16[(size_t)node * NCP + c]);
        float x = activeC ? (acc0 + acc1 + selfv * invdeg[node] + bb) : -INFINITY;
        float mx = x;
        for (int off = 16; off; off >>= 1) mx = fmaxf(mx, __shfl_xor(mx, off));
        float e = activeC ? expf(x - mx) : 0.f;
        float s = e;
        for (int off = 16; off; off >>= 1) s += __shfl_xor(s, off);
        float fx = e / s;
        if (activeC) {
            FX[(size_t)node * NC + c] = fx;
            FX16[(size_t)node * NCP + c] = __float2half(fx);
            lacc += log1pf(-fx * fx);
        } else {
            FX16[(size_t)node * NCP + c] = __float2half(0.f);  // zero the pad
        }
    }
    lacc += __shfl_xor(lacc, 32);
    __shared__ float part[4][NC];
    if (half == 0 && activeC) part[waveInBlock][c] = lacc;
    __syncthreads();
    if (threadIdx.x < NC) {
        float v = part[0][threadIdx.x] + part[1][threadIdx.x] +
                  part[2][threadIdx.x] + part[3][threadIdx.x];
        atomicAdd(&colsum[threadIdx.x], v);
    }
}

// ---------------- edge loss: one edge per lane, packed half2 dot ----------------
// Reads original (coalesced) src/dst/w arrays; gathers two 64 B FX16 rows per lane.
__global__ void edge_loss_flat(const int* __restrict__ src, const int* __restrict__ dst,
                               const float* __restrict__ w, const uint4* __restrict__ FX16u,
                               float* __restrict__ mse) {
    int e = blockIdx.x * blockDim.x + threadIdx.x;
    float v = 0.f;
    if (e < N_EDGES) {
        int s = src[e], d = dst[e];
        const uint4* rs = FX16u + (size_t)s * 4;   // 32 halves = 4 uint4
        const uint4* rd = FX16u + (size_t)d * 4;
        __half2 acc[4];
#pragma unroll
        for (int i = 0; i < 4; ++i) acc[i] = __half2half2(__float2half(0.f));
#pragma unroll
        for (int i = 0; i < 4; ++i) {
            uint4 a = rs[i];
            uint4 b = rd[i];
            acc[0] = __hfma2(*(const __half2*)&a.x, *(const __half2*)&b.x, acc[0]);
            acc[1] = __hfma2(*(const __half2*)&a.y, *(const __half2*)&b.y, acc[1]);
            acc[2] = __hfma2(*(const __half2*)&a.z, *(const __half2*)&b.z, acc[2]);
            acc[3] = __hfma2(*(const __half2*)&a.w, *(const __half2*)&b.w, acc[3]);
        }
        float ff = 0.f;
#pragma unroll
        for (int i = 0; i < 4; ++i)
            ff += __low2float(acc[i]) + __high2float(acc[i]);
        float diff = ff - w[e];
        v = diff * diff;
    }
    for (int off = 32; off > 0; off >>= 1) v += __shfl_down(v, off);
    __shared__ float ps[4];
    int lane = threadIdx.x & 63, wv = threadIdx.x >> 6;
    if (lane == 0) ps[wv] = v;
    __syncthreads();
    if (threadIdx.x == 0) atomicAdd(mse, ps[0] + ps[1] + ps[2] + ps[3]);
}

// ---------------- finalize: preg + loss ----------------
__global__ void finalize(const float* __restrict__ colsum, const float* __restrict__ mse,
                         float* __restrict__ out_loss) {
    int c = threadIdx.x;
    float term = 0.f;
    if (c < NC) term = logf(1.0001f - expf(colsum[c]));
    for (int off = 32; off > 0; off >>= 1) term += __shfl_down(term, off);
    if (threadIdx.x == 0) {
        float preg = -term;
        out_loss[0] = mse[0] / (float)N_EDGES + REG_C * preg;
    }
}

extern "C" void kernel_launch(void* const* d_in, const int* in_sizes, int n_in,
                              void* d_out, int out_size, void* d_ws, size_t ws_size,
                              hipStream_t stream) {
    const float* x  = (const float*)d_in[0];
    const int*   ei = (const int*)d_in[1];
    const float* ea = (const float*)d_in[2];
    const float* W1 = (const float*)d_in[3];
    const float* b1 = (const float*)d_in[4];
    const float* W2 = (const float*)d_in[5];
    const float* b2 = (const float*)d_in[6];
    const int* srcI = ei;
    const int* dstI = ei + N_EDGES;

    float* FX   = (float*)d_out;
    float* loss = FX + (size_t)N_NODES * NC;

    // workspace layout -- explicit float offsets, all vector arrays 16 B aligned
    float* ws = (float*)d_ws;
    float*    deg    = ws;                          // [0, 100000)
    float*    dinv   = ws + 100000;                 // [100000, 200000)
    float*    invdeg = ws + 200000;                 // [200000, 300000)
    _Float16* h1h    = (_Float16*)(ws + 300000);    // 64N halves = 3.2M floats
    float*    h2     = ws + 3500000;                // 64N floats = 6.4M
    __half*   hh16   = (__half*)(ws + 9900000);     // 32N halves = 1.6M floats
    __half*   fx16   = (__half*)(ws + 11500000);    // 32N halves = 1.6M floats
    float*    colsum = ws + 13100000;               // 32
    float*    mse    = ws + 13100032;               // 1 (+pad)
    int*      count  = (int*)(ws + 13100064);       // N
    int*      cursor = (int*)(ws + 13200064);       // N
    int*      rowptr = (int*)(ws + 13300064);       // N+1
    int*      bsum   = (int*)(ws + 13400068);       // 130
    int2*     edata  = (int2*)(ws + 13400200);      // E int2 = 8 MB

    hipMemsetAsync(deg, 0, N_NODES * sizeof(float), stream);
    hipMemsetAsync(count, 0, N_NODES * sizeof(int), stream);
    hipMemsetAsync(cursor, 0, N_NODES * sizeof(int), stream);
    hipMemsetAsync(colsum, 0, 33 * sizeof(float), stream);

    hist_deg<<<(N_EDGES + 255) / 256, 256, 0, stream>>>(dstI, ea, count, deg);
    compute_dinv<<<(N_NODES + 255) / 256, 256, 0, stream>>>(deg, dinv, invdeg);
    scan_p1<<<SCAN_NT, 256, 0, stream>>>(count, bsum);
    scan_p2<<<1, 128, 0, stream>>>(bsum, rowptr);
    scan_p3<<<SCAN_NT, 256, 0, stream>>>(count, bsum, rowptr);
    sort_scatter<<<(N_EDGES + 255) / 256, 256, 0, stream>>>(srcI, dstI, ea, dinv,
                                                            rowptr, cursor, edata);
    linear64_mfma<<<1563, 256, 0, stream>>>(x, W1, h1h);
    agg64_fused<<<(N_NODES + 3) / 4, 256, 0, stream>>>(rowptr, edata, h1h, invdeg, b1, h2);
    linear30<<<(N_NODES + 7) / 8, 256, 0, stream>>>(h2, W2, hh16);
    agg30_softmax_colsum<<<4096, 256, 0, stream>>>(rowptr, edata, hh16, invdeg, b2,
                                                   FX, fx16, colsum);
    edge_loss_flat<<<(N_EDGES + 255) / 256, 256, 0, stream>>>(srcI, dstI, ea,
                                                              (const uint4*)fx16, mse);
    finalize<<<1, 64, 0, stream>>>(colsum, mse, loss);
}

// Round 6
// 395.647 us; speedup vs baseline: 2.7577x; 1.1822x over previous
//
#include <hip/hip_runtime.h>
#include <hip/hip_fp16.h>
#include <math.h>

#define N_NODES 100000
#define N_EDGES 1000000
#define IN_DIM 64
#define HID 64
#define NC 30
#define NCP 32              // padded row width for fp16 feature rows (64 B)
#define REG_C 0.01f

#define SCAN_TILE 1024
#define SCAN_NT ((N_NODES + SCAN_TILE - 1) / SCAN_TILE)   // 98
#define NTILES (N_NODES / 16)                             // 6250 exactly
#define HIST_BLOCKS ((N_EDGES + 255) / 256)               // 3907
#define GEMM_BLOCKS 1024
#define DEG_SCALE 16777216.0f                              // 2^24 fixed point

typedef _Float16 half8 __attribute__((ext_vector_type(8)));
typedef float f32x4 __attribute__((ext_vector_type(4)));

// ------- fused: u64 packed histogram (count|deg) + rank  AND  h1 = fp16(x@W1) -------
// Blocks [0, HIST_BLOCKS): one packed atomic per edge; returned old value gives the
// edge's within-bin rank (replaces sort-phase cursor atomics entirely).
// Blocks [HIST_BLOCKS, +GEMM_BLOCKS): MFMA GEMM, grid-stride over 16-node tiles.
__global__ void hist_gemm(const int* __restrict__ dst, const float* __restrict__ w,
                          unsigned long long* __restrict__ packed, int* __restrict__ rank,
                          const float* __restrict__ X, const float* __restrict__ W,
                          _Float16* __restrict__ H16) {
    if (blockIdx.x < HIST_BLOCKS) {
        int e = blockIdx.x * 256 + threadIdx.x;
        if (e < N_EDGES) {
            int d = dst[e];
            unsigned long long pk = (1ULL << 40) |
                (unsigned long long)__float2uint_rn(w[e] * DEG_SCALE);
            unsigned long long old = atomicAdd(&packed[d], pk);
            rank[e] = (int)(old >> 40);
        }
        return;
    }
    // ---- GEMM part ----
    const int lane = threadIdx.x & 63;
    const int wave = threadIdx.x >> 6;
    const int q = lane >> 4;
    const int l = lane & 15;
    // B fragments: bfrag[kb][t][j] = W[(kb*32 + q*8 + j)*64 + t*16 + l]
    half8 bfrag[2][4];
#pragma unroll
    for (int kb = 0; kb < 2; ++kb)
#pragma unroll
        for (int t = 0; t < 4; ++t)
#pragma unroll
            for (int j = 0; j < 8; ++j)
                bfrag[kb][t][j] = (_Float16)W[(kb * 32 + q * 8 + j) * 64 + t * 16 + l];

    const int gb = blockIdx.x - HIST_BLOCKS;
    const int waveStride = GEMM_BLOCKS * 4;
    for (int ntile = gb * 4 + wave; ntile < NTILES; ntile += waveStride) {
        const int node0 = ntile * 16;
        const float* arow = X + (size_t)(node0 + l) * 64 + q * 8;
        half8 af0, af1;
#pragma unroll
        for (int j = 0; j < 8; ++j) {
            af0[j] = (_Float16)arow[j];
            af1[j] = (_Float16)arow[32 + j];
        }
        f32x4 acc[4];
#pragma unroll
        for (int t = 0; t < 4; ++t) acc[t] = (f32x4){0.f, 0.f, 0.f, 0.f};
#pragma unroll
        for (int t = 0; t < 4; ++t) {
            acc[t] = __builtin_amdgcn_mfma_f32_16x16x32_f16(af0, bfrag[0][t], acc[t], 0, 0, 0);
            acc[t] = __builtin_amdgcn_mfma_f32_16x16x32_f16(af1, bfrag[1][t], acc[t], 0, 0, 0);
        }
#pragma unroll
        for (int t = 0; t < 4; ++t)
#pragma unroll
            for (int r = 0; r < 4; ++r)
                H16[(size_t)(node0 + q * 4 + r) * 64 + t * 16 + l] = (_Float16)acc[t][r];
    }
}

// ---------------- decode packed -> count / dinv / invdeg ----------------
__global__ void compute_dinv(const unsigned long long* __restrict__ packed,
                             int* __restrict__ count, float* __restrict__ dinv,
                             float* __restrict__ invdeg) {
    int n = blockIdx.x * blockDim.x + threadIdx.x;
    if (n < N_NODES) {
        unsigned long long p = packed[n];
        count[n] = (int)(p >> 40);
        float d = (float)(p & 0xFFFFFFFFFFULL) * (1.0f / DEG_SCALE) + 1.0f; // self-loop
        dinv[n] = rsqrtf(d);
        invdeg[n] = 1.0f / d;
    }
}

// ---------------- 3-phase exclusive scan of count -> rowptr ----------------
__global__ void scan_p1(const int* __restrict__ count, int* __restrict__ blocksum) {
    __shared__ int s[256];
    int base = blockIdx.x * SCAN_TILE;
    int tid = threadIdx.x;
    int sum = 0;
#pragma unroll
    for (int j = 0; j < 4; ++j) {
        int i = base + tid * 4 + j;
        if (i < N_NODES) sum += count[i];
    }
    s[tid] = sum;
    __syncthreads();
    for (int off = 128; off; off >>= 1) {
        if (tid < off) s[tid] += s[tid + off];
        __syncthreads();
    }
    if (tid == 0) blocksum[blockIdx.x] = s[0];
}

__global__ void scan_p2(int* __restrict__ blocksum, int* __restrict__ rowptr) {
    __shared__ int s[128];
    int tid = threadIdx.x;
    s[tid] = (tid < SCAN_NT) ? blocksum[tid] : 0;
    __syncthreads();
    if (tid == 0) {
        int run = 0;
        for (int i = 0; i < SCAN_NT; ++i) { int v = s[i]; s[i] = run; run += v; }
        rowptr[N_NODES] = N_EDGES;
    }
    __syncthreads();
    if (tid < SCAN_NT) blocksum[tid] = s[tid];
}

__global__ void scan_p3(const int* __restrict__ count, const int* __restrict__ blocksum,
                        int* __restrict__ rowptr) {
    __shared__ int s[256];
    int base = blockIdx.x * SCAN_TILE;
    int tid = threadIdx.x;
    int v[4];
    int sum = 0;
#pragma unroll
    for (int j = 0; j < 4; ++j) {
        int i = base + tid * 4 + j;
        v[j] = (i < N_NODES) ? count[i] : 0;
        sum += v[j];
    }
    s[tid] = sum;
    __syncthreads();
    for (int off = 1; off < 256; off <<= 1) {
        int t = (tid >= off) ? s[tid - off] : 0;
        __syncthreads();
        s[tid] += t;
        __syncthreads();
    }
    int run = blocksum[blockIdx.x] + (tid ? s[tid - 1] : 0);
#pragma unroll
    for (int j = 0; j < 4; ++j) {
        int i = base + tid * 4 + j;
        if (i < N_NODES) rowptr[i] = run;
        run += v[j];
    }
}

// ---------------- atomic-free placement: edata[rowptr[d]+rank[e]] = (src, norm) ----
__global__ void sort_scatter(const int* __restrict__ src, const int* __restrict__ dst,
                             const float* __restrict__ w, const float* __restrict__ dinv,
                             const int* __restrict__ rowptr, const int* __restrict__ rank,
                             int2* __restrict__ edata) {
    int e = blockIdx.x * blockDim.x + threadIdx.x;
    if (e < N_EDGES) {
        int s = src[e], d = dst[e];
        float norm = dinv[s] * w[e] * dinv[d];
        edata[rowptr[d] + rank[e]] = make_int2(s, __float_as_int(norm));
    }
}

// ---------------- gather-aggregate 64-dim (fp16 rows) + self-loop + bias + relu ----
__global__ void agg64_fused(const int* __restrict__ rowptr, const int2* __restrict__ edata,
                            const _Float16* __restrict__ H16, const float* __restrict__ invdeg,
                            const float* __restrict__ b1, _Float16* __restrict__ h2h) {
    int node = blockIdx.x * 4 + (threadIdx.x >> 6);
    int lane = threadIdx.x & 63;
    if (node >= N_NODES) return;
    int p = rowptr[node], end = rowptr[node + 1];
    float a0 = 0.f, a1 = 0.f, a2 = 0.f, a3 = 0.f;
    for (; p + 3 < end; p += 4) {
        int2 e0 = edata[p], e1 = edata[p + 1], e2 = edata[p + 2], e3 = edata[p + 3];
        a0 += __int_as_float(e0.y) * (float)H16[(size_t)e0.x * 64 + lane];
        a1 += __int_as_float(e1.y) * (float)H16[(size_t)e1.x * 64 + lane];
        a2 += __int_as_float(e2.y) * (float)H16[(size_t)e2.x * 64 + lane];
        a3 += __int_as_float(e3.y) * (float)H16[(size_t)e3.x * 64 + lane];
    }
    for (; p < end; ++p) {
        int2 e0 = edata[p];
        a0 += __int_as_float(e0.y) * (float)H16[(size_t)e0.x * 64 + lane];
    }
    float v = (a0 + a1) + (a2 + a3) +
              (float)H16[(size_t)node * 64 + lane] * invdeg[node] + b1[lane];
    h2h[(size_t)node * 64 + lane] = (_Float16)fmaxf(v, 0.f);
}

// ---------------- hh16 = fp16(h2 @ W2), padded 32-wide rows (64 B, zero-filled) ----
__global__ void linear30(const _Float16* __restrict__ H, const float* __restrict__ W2,
                         __half* __restrict__ HH16) {
    __shared__ float sW[64 * NC];
    __shared__ float sH[8 * 64];
    for (int i = threadIdx.x; i < 64 * NC; i += blockDim.x) sW[i] = W2[i];
    int node0 = blockIdx.x * 8;
    for (int i = threadIdx.x; i < 8 * 64; i += blockDim.x) {
        int n = node0 + (i >> 6);
        sH[i] = (n < N_NODES) ? (float)H[(size_t)n * 64 + (i & 63)] : 0.f;
    }
    __syncthreads();
    int ln = threadIdx.x >> 5;
    int c = threadIdx.x & 31;
    int node = node0 + ln;
    if (node < N_NODES) {
        float acc = 0.f;
        if (c < NC) {
#pragma unroll
            for (int k = 0; k < 64; ++k) acc += sH[ln * 64 + k] * sW[k * NC + c];
        }
        HH16[(size_t)node * NCP + c] = __float2half(acc);   // c>=NC writes 0
    }
}

// ---------------- gather-aggregate 30-dim + softmax -> FX/FX16 + colsum ------------
__global__ void agg30_softmax_colsum(const int* __restrict__ rowptr, const int2* __restrict__ edata,
                                     const __half* __restrict__ HH16,
                                     const float* __restrict__ invdeg,
                                     const float* __restrict__ b2, float* __restrict__ FX,
                                     __half* __restrict__ FX16, float* __restrict__ colsum) {
    const int lane = threadIdx.x & 63;
    const int waveInBlock = threadIdx.x >> 6;
    const int half = lane >> 5;
    const int c = lane & 31;
    const bool activeC = (c < NC);
    const int wavesTotal = gridDim.x * (blockDim.x >> 6);
    const int w0 = blockIdx.x * (blockDim.x >> 6) + waveInBlock;

    const float bb = activeC ? b2[c] : 0.f;
    float lacc = 0.f;

    for (int pair = w0; pair < N_NODES / 2; pair += wavesTotal) {
        const int node = pair * 2 + half;
        int p = rowptr[node], end = rowptr[node + 1];
        float acc0 = 0.f, acc1 = 0.f;
        for (; p + 1 < end; p += 2) {
            int2 e0 = edata[p];
            int2 e1 = edata[p + 1];
            float v0 = __half2float(HH16[(size_t)e0.x * NCP + c]);
            float v1 = __half2float(HH16[(size_t)e1.x * NCP + c]);
            acc0 += __int_as_float(e0.y) * v0;
            acc1 += __int_as_float(e1.y) * v1;
        }
        if (p < end) {
            int2 e0 = edata[p];
            acc0 += __int_as_float(e0.y) * __half2float(HH16[(size_t)e0.x * NCP + c]);
        }
        float selfv = __half2float(HH16[(size_t)node * NCP + c]);
        float x = activeC ? (acc0 + acc1 + selfv * invdeg[node] + bb) : -INFINITY;
        float mx = x;
        for (int off = 16; off; off >>= 1) mx = fmaxf(mx, __shfl_xor(mx, off));
        float e = activeC ? expf(x - mx) : 0.f;
        float s = e;
        for (int off = 16; off; off >>= 1) s += __shfl_xor(s, off);
        float fx = e / s;
        if (activeC) {
            FX[(size_t)node * NC + c] = fx;
            FX16[(size_t)node * NCP + c] = __float2half(fx);
            lacc += log1pf(-fx * fx);
        } else {
            FX16[(size_t)node * NCP + c] = __float2half(0.f);  // zero the pad
        }
    }
    lacc += __shfl_xor(lacc, 32);
    __shared__ float part[4][NC];
    if (half == 0 && activeC) part[waveInBlock][c] = lacc;
    __syncthreads();
    if (threadIdx.x < NC) {
        float v = part[0][threadIdx.x] + part[1][threadIdx.x] +
                  part[2][threadIdx.x] + part[3][threadIdx.x];
        atomicAdd(&colsum[threadIdx.x], v);
    }
}

// ---------------- edge loss: one edge per lane, packed half2 dot ----------------
__global__ void edge_loss_flat(const int* __restrict__ src, const int* __restrict__ dst,
                               const float* __restrict__ w, const uint4* __restrict__ FX16u,
                               float* __restrict__ mse) {
    int e = blockIdx.x * blockDim.x + threadIdx.x;
    float v = 0.f;
    if (e < N_EDGES) {
        int s = src[e], d = dst[e];
        const uint4* rs = FX16u + (size_t)s * 4;   // 32 halves = 4 uint4
        const uint4* rd = FX16u + (size_t)d * 4;
        __half2 acc[4];
#pragma unroll
        for (int i = 0; i < 4; ++i) acc[i] = __half2half2(__float2half(0.f));
#pragma unroll
        for (int i = 0; i < 4; ++i) {
            uint4 a = rs[i];
            uint4 b = rd[i];
            acc[0] = __hfma2(*(const __half2*)&a.x, *(const __half2*)&b.x, acc[0]);
            acc[1] = __hfma2(*(const __half2*)&a.y, *(const __half2*)&b.y, acc[1]);
            acc[2] = __hfma2(*(const __half2*)&a.z, *(const __half2*)&b.z, acc[2]);
            acc[3] = __hfma2(*(const __half2*)&a.w, *(const __half2*)&b.w, acc[3]);
        }
        float ff = 0.f;
#pragma unroll
        for (int i = 0; i < 4; ++i)
            ff += __low2float(acc[i]) + __high2float(acc[i]);
        float diff = ff - w[e];
        v = diff * diff;
    }
    for (int off = 32; off > 0; off >>= 1) v += __shfl_down(v, off);
    __shared__ float ps[4];
    int lane = threadIdx.x & 63, wv = threadIdx.x >> 6;
    if (lane == 0) ps[wv] = v;
    __syncthreads();
    if (threadIdx.x == 0) atomicAdd(mse, ps[0] + ps[1] + ps[2] + ps[3]);
}

// ---------------- finalize: preg + loss ----------------
__global__ void finalize(const float* __restrict__ colsum, const float* __restrict__ mse,
                         float* __restrict__ out_loss) {
    int c = threadIdx.x;
    float term = 0.f;
    if (c < NC) term = logf(1.0001f - expf(colsum[c]));
    for (int off = 32; off > 0; off >>= 1) term += __shfl_down(term, off);
    if (threadIdx.x == 0) {
        float preg = -term;
        out_loss[0] = mse[0] / (float)N_EDGES + REG_C * preg;
    }
}

extern "C" void kernel_launch(void* const* d_in, const int* in_sizes, int n_in,
                              void* d_out, int out_size, void* d_ws, size_t ws_size,
                              hipStream_t stream) {
    const float* x  = (const float*)d_in[0];
    const int*   ei = (const int*)d_in[1];
    const float* ea = (const float*)d_in[2];
    const float* W1 = (const float*)d_in[3];
    const float* b1 = (const float*)d_in[4];
    const float* W2 = (const float*)d_in[5];
    const float* b2 = (const float*)d_in[6];
    const int* srcI = ei;
    const int* dstI = ei + N_EDGES;

    float* FX   = (float*)d_out;
    float* loss = FX + (size_t)N_NODES * NC;

    // workspace layout -- explicit float-element offsets; 8B/16B alignment verified
    float* ws = (float*)d_ws;
    float*    dinv   = ws;                            // N
    float*    invdeg = ws + 100000;                   // N
    _Float16* h1h    = (_Float16*)(ws + 200000);      // 64N halves = 3.2M floats
    _Float16* h2h    = (_Float16*)(ws + 3400000);     // 64N halves = 3.2M floats
    __half*   hh16   = (__half*)(ws + 6600000);       // 32N halves = 1.6M floats
    __half*   fx16   = (__half*)(ws + 8200000);       // 32N halves = 1.6M floats
    float*    colsum = ws + 9800000;                  // 32
    float*    mse    = ws + 9800032;                  // 1 (+pad to 64)
    int*      count  = (int*)(ws + 9800064);          // N
    int*      rowptr = (int*)(ws + 9900064);          // N+1 (+pad)
    int*      bsum   = (int*)(ws + 10000066);         // 130 (+pad to even)
    unsigned long long* packed = (unsigned long long*)(ws + 10000200);  // N u64 = 200000 floats
    int*      rank   = (int*)(ws + 10200200);         // E
    int2*     edata  = (int2*)(ws + 11200200);        // E int2 = 2M floats

    hipMemsetAsync(packed, 0, N_NODES * sizeof(unsigned long long), stream);
    hipMemsetAsync(colsum, 0, 33 * sizeof(float), stream);

    hist_gemm<<<HIST_BLOCKS + GEMM_BLOCKS, 256, 0, stream>>>(dstI, ea, packed, rank,
                                                             x, W1, h1h);
    compute_dinv<<<(N_NODES + 255) / 256, 256, 0, stream>>>(packed, count, dinv, invdeg);
    scan_p1<<<SCAN_NT, 256, 0, stream>>>(count, bsum);
    scan_p2<<<1, 128, 0, stream>>>(bsum, rowptr);
    scan_p3<<<SCAN_NT, 256, 0, stream>>>(count, bsum, rowptr);
    sort_scatter<<<(N_EDGES + 255) / 256, 256, 0, stream>>>(srcI, dstI, ea, dinv,
                                                            rowptr, rank, edata);
    agg64_fused<<<(N_NODES + 3) / 4, 256, 0, stream>>>(rowptr, edata, h1h, invdeg, b1, h2h);
    linear30<<<(N_NODES + 7) / 8, 256, 0, stream>>>(h2h, W2, hh16);
    agg30_softmax_colsum<<<4096, 256, 0, stream>>>(rowptr, edata, hh16, invdeg, b2,
                                                   FX, fx16, colsum);
    edge_loss_flat<<<(N_EDGES + 255) / 256, 256, 0, stream>>>(srcI, dstI, ea,
                                                              (const uint4*)fx16, mse);
    finalize<<<1, 64, 0, stream>>>(colsum, mse, loss);
}